// Round 2
// baseline (493.506 us; speedup 1.0000x reference)
//
#include <hip/hip_runtime.h>
#include <hip/hip_bf16.h>
#include <cstdint>
#include <cstddef>

#define B_ROWS 8192
#define N_COLS 4096
#define P_BLK 8
#define D_BLK 512
#define EPSV 1e-5f

typedef __bf16 bf16x8 __attribute__((ext_vector_type(8)));
typedef float f32x4 __attribute__((ext_vector_type(4)));

// ---------------------------------------------------------------------------
// async 16B global -> LDS (HW: LDS dst = wave-uniform base + lane*16)
// ---------------------------------------------------------------------------
__device__ __forceinline__ void async_ld16(const void* g, void* l) {
    __builtin_amdgcn_global_load_lds(
        (const __attribute__((address_space(1))) void*)g,
        (__attribute__((address_space(3))) void*)l,
        16, 0, 0);
}

// ---------------------------------------------------------------------------
// x fp32 -> bf16, 8 elements/thread
// ---------------------------------------------------------------------------
__global__ __launch_bounds__(256) void cvt_x_k(const float* __restrict__ x,
                                               __hip_bfloat16* __restrict__ xb) {
    size_t i = ((size_t)blockIdx.x * 256 + threadIdx.x) * 8;
    float4 v0 = *(const float4*)(x + i);
    float4 v1 = *(const float4*)(x + i + 4);
    union { __hip_bfloat16 h[8]; uint4 u; } r;
    r.h[0] = __float2bfloat16(v0.x); r.h[1] = __float2bfloat16(v0.y);
    r.h[2] = __float2bfloat16(v0.z); r.h[3] = __float2bfloat16(v0.w);
    r.h[4] = __float2bfloat16(v1.x); r.h[5] = __float2bfloat16(v1.y);
    r.h[6] = __float2bfloat16(v1.z); r.h[7] = __float2bfloat16(v1.w);
    *(uint4*)(xb + i) = r.u;
}

// ---------------------------------------------------------------------------
// W[p,d,e] fp32 -> Wt[p,e,d] bf16, optional per-d scale (for W2' = a[d]*W2)
// block (32,8), grid (16,16,8)
// ---------------------------------------------------------------------------
__global__ __launch_bounds__(256) void tr_w_k(const float* __restrict__ W,
                                              const float* __restrict__ scale,
                                              __hip_bfloat16* __restrict__ Wt) {
    __shared__ float t[32][33];
    int p = blockIdx.z;
    int d0 = blockIdx.x * 32, e0 = blockIdx.y * 32;
    const float* Wp = W + (size_t)p * D_BLK * D_BLK;
    for (int j = 0; j < 32; j += 8) {
        int d = d0 + threadIdx.y + j;
        float v = Wp[(size_t)d * D_BLK + e0 + threadIdx.x];
        if (scale) v *= scale[p * D_BLK + d];
        t[threadIdx.y + j][threadIdx.x] = v;
    }
    __syncthreads();
    __hip_bfloat16* Wtp = Wt + (size_t)p * D_BLK * D_BLK;
    for (int j = 0; j < 32; j += 8) {
        int e = e0 + threadIdx.y + j;
        Wtp[(size_t)e * D_BLK + d0 + threadIdx.x] =
            __float2bfloat16(t[threadIdx.x][threadIdx.y + j]);
    }
}

// ---------------------------------------------------------------------------
// finalize BN: a = bn_w * rsqrt(var+eps), c = bn_b - mean*a
// ---------------------------------------------------------------------------
__global__ __launch_bounds__(256) void finalize_k(const float* __restrict__ sum,
                                                  const float* __restrict__ sumsq,
                                                  const float* __restrict__ bnw,
                                                  const float* __restrict__ bnb,
                                                  float* __restrict__ a,
                                                  float* __restrict__ c) {
    int i = blockIdx.x * 256 + threadIdx.x;
    float m = sum[i] * (1.0f / B_ROWS);
    float var = sumsq[i] * (1.0f / B_ROWS) - m * m;
    float ai = bnw[i] * rsqrtf(var + EPSV);
    a[i] = ai;
    c[i] = bnb[i] - m * ai;
}

// ---------------------------------------------------------------------------
// bias2'[col] = bias2[col] + sum_d c[p*D+d] * W2[p,d,e]
// ---------------------------------------------------------------------------
__global__ __launch_bounds__(256) void bias2p_k(const float* __restrict__ W2,
                                                const float* __restrict__ c,
                                                const float* __restrict__ bias2,
                                                float* __restrict__ out) {
    int col = blockIdx.x * 256 + threadIdx.x;
    int p = col >> 9;
    int e = col & (D_BLK - 1);
    const float* Wp = W2 + (size_t)p * D_BLK * D_BLK + e;
    const float* cp = c + p * D_BLK;
    float acc = 0.0f;
    for (int d = 0; d < D_BLK; d++) acc += cp[d] * Wp[(size_t)d * D_BLK];
    out[col] = bias2[col] + acc;
}

// ---------------------------------------------------------------------------
// GEMM core: 128x128 tile, BK=32, double-buffered LDS, 4 waves (2x2),
// each wave 64x64 via 4x4 mfma_f32_16x16x32_bf16.
// LDS bank swizzle: chunk position c of row r holds global chunk c^((r>>1)&3)
// (realized by permuting the *source* address; global_load_lds dst is fixed
//  at base+lane*16). Fragment read offset folds to one per-lane constant.
// ---------------------------------------------------------------------------
__device__ __forceinline__ void gemm_core(const __hip_bfloat16* __restrict__ A,
                                          const __hip_bfloat16* __restrict__ Bt,
                                          f32x4 acc[4][4]) {
    __shared__ __hip_bfloat16 As[2][128 * 32];
    __shared__ __hip_bfloat16 Bs[2][128 * 32];

    const int tid = threadIdx.x;
    const int lane = tid & 63;
    const int wave = tid >> 6;
    const int wm = (wave >> 1) * 64;
    const int wn = (wave & 1) * 64;
    const int row_base = blockIdx.x * 128;
    const int col_base = blockIdx.y * 128;
    const int p = col_base >> 9;
    const int ebase = col_base & (D_BLK - 1);

    // staging: thread tid fills LDS row ar=tid>>2, chunk position c4=tid&3;
    // it must FETCH global chunk q4 = c4 ^ ((ar>>1)&3) = c4 ^ ((tid>>3)&3)
    const int ar = tid >> 2;
    const int c4 = tid & 3;
    const int kq8 = (c4 ^ ((tid >> 3) & 3)) * 8;   // fetched k-offset (elements)
    const int dst_off = ar * 32 + c4 * 8;          // == tid*8 elements = lane*16B

    const __hip_bfloat16* a_src0 = A + (size_t)(row_base + ar) * N_COLS + p * D_BLK + kq8;
    const __hip_bfloat16* a_src1 = a_src0 + (size_t)64 * N_COLS;
    const __hip_bfloat16* b_src0 = Bt + (size_t)(p * D_BLK + ebase + ar) * D_BLK + kq8;
    const __hip_bfloat16* b_src1 = b_src0 + (size_t)64 * D_BLK;

    // fragment read: lane wants row R=...+fm, k-chunk kq=lane>>4; its LDS chunk
    // position is kq ^ ((R>>1)&3) = kq ^ ((fm>>1)&3)  (row bases are mult of 16)
    const int fm = lane & 15;
    const int fkoff = ((lane >> 4) ^ ((fm >> 1) & 3)) * 8;

    for (int i = 0; i < 4; i++)
        for (int j = 0; j < 4; j++)
            acc[i][j] = (f32x4){0.0f, 0.0f, 0.0f, 0.0f};

    // prologue: stage slab 0 into buffer 0
    async_ld16(a_src0, &As[0][dst_off]);
    async_ld16(a_src1, &As[0][dst_off + 64 * 32]);
    async_ld16(b_src0, &Bs[0][dst_off]);
    async_ld16(b_src1, &Bs[0][dst_off + 64 * 32]);
    a_src0 += 32; a_src1 += 32; b_src0 += 32; b_src1 += 32;

    for (int k = 0; k < 16; k++) {
        const int cur = k & 1;
        // drains slab-k loads (issued one full iteration ago -> cheap) and
        // guarantees buf[1-cur] readers from iter k-1 are done before overwrite
        __syncthreads();
        if (k < 15) {
            const int nxt = 1 - cur;
            async_ld16(a_src0, &As[nxt][dst_off]);
            async_ld16(a_src1, &As[nxt][dst_off + 64 * 32]);
            async_ld16(b_src0, &Bs[nxt][dst_off]);
            async_ld16(b_src1, &Bs[nxt][dst_off + 64 * 32]);
            a_src0 += 32; a_src1 += 32; b_src0 += 32; b_src1 += 32;
        }

        bf16x8 af[4], bfr[4];
#pragma unroll
        for (int i = 0; i < 4; i++)
            af[i] = *(const bf16x8*)&As[cur][(wm + i * 16 + fm) * 32 + fkoff];
#pragma unroll
        for (int j = 0; j < 4; j++)
            bfr[j] = *(const bf16x8*)&Bs[cur][(wn + j * 16 + fm) * 32 + fkoff];
#pragma unroll
        for (int i = 0; i < 4; i++)
#pragma unroll
            for (int j = 0; j < 4; j++)
                acc[i][j] = __builtin_amdgcn_mfma_f32_16x16x32_bf16(
                    af[i], bfr[j], acc[i][j], 0, 0, 0);
    }
}

// ---------------------------------------------------------------------------
// GEMM1: h = x @ W1 + bias1 (bf16 out), plus per-column sum / sumsq atomics
// ---------------------------------------------------------------------------
__global__ __launch_bounds__(256, 4) void gemm1_k(const __hip_bfloat16* __restrict__ xb,
                                                  const __hip_bfloat16* __restrict__ w1t,
                                                  const float* __restrict__ bias1,
                                                  __hip_bfloat16* __restrict__ h,
                                                  float* __restrict__ sum,
                                                  float* __restrict__ sumsq) {
    f32x4 acc[4][4];
    gemm_core(xb, w1t, acc);

    const int tid = threadIdx.x;
    const int lane = tid & 63;
    const int wave = tid >> 6;
    const int wm = (wave >> 1) * 64;
    const int wn = (wave & 1) * 64;
    const int row_base = blockIdx.x * 128;
    const int col_base = blockIdx.y * 128;
    const int cr = (lane >> 4) * 4;   // C/D: row = quad*4 + reg
    const int cc = lane & 15;         // C/D: col = lane&15

#pragma unroll
    for (int j = 0; j < 4; j++) {
        const int col = col_base + wn + j * 16 + cc;
        const float b1 = bias1[col];
        float s = 0.0f, sq = 0.0f;
#pragma unroll
        for (int i = 0; i < 4; i++) {
            const int row0 = row_base + wm + i * 16 + cr;
#pragma unroll
            for (int r = 0; r < 4; r++) {
                float v = acc[i][j][r] + b1;
                h[(size_t)(row0 + r) * N_COLS + col] = __float2bfloat16(v);
                s += v;
                sq += v * v;
            }
        }
        s  += __shfl_xor(s, 16);  s  += __shfl_xor(s, 32);
        sq += __shfl_xor(sq, 16); sq += __shfl_xor(sq, 32);
        if (lane < 16) {
            atomicAdd(&sum[col], s);
            atomicAdd(&sumsq[col], sq);
        }
    }
}

// ---------------------------------------------------------------------------
// GEMM2: o3 = h_bf16 @ W2' + bias2' + x ; out = (g + sig(be*o3)*(1-g)) * o3
// residual read from the bf16 copy xb (halves residual fetch traffic)
// ---------------------------------------------------------------------------
__global__ __launch_bounds__(256, 4) void gemm2_k(const __hip_bfloat16* __restrict__ h,
                                                  const __hip_bfloat16* __restrict__ w2t,
                                                  const float* __restrict__ bias2p,
                                                  const __hip_bfloat16* __restrict__ xb,
                                                  const float* __restrict__ gamma3,
                                                  const float* __restrict__ beta3,
                                                  float* __restrict__ out) {
    f32x4 acc[4][4];
    gemm_core(h, w2t, acc);

    const int tid = threadIdx.x;
    const int lane = tid & 63;
    const int wave = tid >> 6;
    const int wm = (wave >> 1) * 64;
    const int wn = (wave & 1) * 64;
    const int row_base = blockIdx.x * 128;
    const int col_base = blockIdx.y * 128;
    const int cr = (lane >> 4) * 4;
    const int cc = lane & 15;

#pragma unroll
    for (int j = 0; j < 4; j++) {
        const int col = col_base + wn + j * 16 + cc;
        const float bb = bias2p[col];
        const float g  = gamma3[col];
        const float be = beta3[col];
#pragma unroll
        for (int i = 0; i < 4; i++) {
            const int row0 = row_base + wm + i * 16 + cr;
#pragma unroll
            for (int r = 0; r < 4; r++) {
                const size_t idx = (size_t)(row0 + r) * N_COLS + col;
                float o3 = acc[i][j][r] + bb + __bfloat162float(xb[idx]);
                float sg = 1.0f / (1.0f + expf(-be * o3));
                out[idx] = (g + sg * (1.0f - g)) * o3;
            }
        }
    }
}

// ---------------------------------------------------------------------------
extern "C" void kernel_launch(void* const* d_in, const int* in_sizes, int n_in,
                              void* d_out, int out_size, void* d_ws, size_t ws_size,
                              hipStream_t stream) {
    const float* x     = (const float*)d_in[0];
    const float* W1    = (const float*)d_in[1];
    const float* bias1 = (const float*)d_in[2];
    const float* W2    = (const float*)d_in[3];
    const float* bias2 = (const float*)d_in[4];
    const float* bnw   = (const float*)d_in[5];
    const float* bnb   = (const float*)d_in[6];
    const float* gam3  = (const float*)d_in[7];
    const float* bet3  = (const float*)d_in[8];
    float* out = (float*)d_out;

    // workspace layout
    char* ws = (char*)d_ws;
    const size_t XB_BYTES = (size_t)B_ROWS * N_COLS * 2;   // 64 MiB
    const size_t H_BYTES  = (size_t)B_ROWS * N_COLS * 2;   // 64 MiB
    const size_t WT_BYTES = (size_t)P_BLK * D_BLK * D_BLK * 2;  // 4 MiB
    const size_t V_BYTES  = (size_t)N_COLS * 4;            // 16 KiB

    __hip_bfloat16* xb   = (__hip_bfloat16*)(ws);
    __hip_bfloat16* hbuf = (__hip_bfloat16*)(ws + XB_BYTES);
    __hip_bfloat16* w1t  = (__hip_bfloat16*)(ws + XB_BYTES + H_BYTES);
    __hip_bfloat16* w2t  = (__hip_bfloat16*)(ws + XB_BYTES + H_BYTES + WT_BYTES);
    float* sums  = (float*)(ws + XB_BYTES + H_BYTES + 2 * WT_BYTES);
    float* sumsq = (float*)((char*)sums + V_BYTES);
    float* a_sc  = (float*)((char*)sums + 2 * V_BYTES);
    float* c_sh  = (float*)((char*)sums + 3 * V_BYTES);
    float* b2p   = (float*)((char*)sums + 4 * V_BYTES);

    (void)in_sizes; (void)n_in; (void)out_size; (void)ws_size;

    // zero the stats accumulators (ws is poisoned 0xAA before every call)
    hipMemsetAsync(sums, 0, 2 * V_BYTES, stream);

    // x -> bf16
    cvt_x_k<<<dim3((B_ROWS * N_COLS) / (256 * 8)), dim3(256), 0, stream>>>(x, xb);
    // W1 -> bf16 transposed [p,e,d]
    tr_w_k<<<dim3(16, 16, 8), dim3(32, 8), 0, stream>>>(W1, nullptr, w1t);
    // GEMM1 + bias + stats
    gemm1_k<<<dim3(B_ROWS / 128, N_COLS / 128), dim3(256), 0, stream>>>(
        xb, w1t, bias1, hbuf, sums, sumsq);
    // BN scale/shift
    finalize_k<<<dim3(N_COLS / 256), dim3(256), 0, stream>>>(sums, sumsq, bnw, bnb, a_sc, c_sh);
    // W2' = a * W2, transposed bf16
    tr_w_k<<<dim3(16, 16, 8), dim3(32, 8), 0, stream>>>(W2, a_sc, w2t);
    // bias2' = bias2 + c @ W2
    bias2p_k<<<dim3(N_COLS / 256), dim3(256), 0, stream>>>(W2, c_sh, bias2, b2p);
    // GEMM2 + residual + gate
    gemm2_k<<<dim3(B_ROWS / 128, N_COLS / 128), dim3(256), 0, stream>>>(
        hbuf, w2t, b2p, xb, gam3, bet3, out);
}

// Round 3
// 402.333 us; speedup vs baseline: 1.2266x; 1.2266x over previous
//
#include <hip/hip_runtime.h>
#include <hip/hip_bf16.h>
#include <cstdint>
#include <cstddef>

#define B_ROWS 8192
#define N_COLS 4096
#define P_BLK 8
#define D_BLK 512
#define EPSV 1e-5f

typedef __bf16 bf16x8 __attribute__((ext_vector_type(8)));
typedef float f32x4 __attribute__((ext_vector_type(4)));

// ---------------------------------------------------------------------------
// async 16B global -> LDS (HW: LDS dst = wave-uniform base + lane*16)
// ---------------------------------------------------------------------------
__device__ __forceinline__ void async_ld16(const void* g, void* l) {
    __builtin_amdgcn_global_load_lds(
        (const __attribute__((address_space(1))) void*)g,
        (__attribute__((address_space(3))) void*)l,
        16, 0, 0);
}

// ---------------------------------------------------------------------------
// block swizzle: flat id n -> (row_tile, col_tile) such that the 4 blocks
// sharing one A-slab (same row-strip, same diagonal block p) are n, n+8,
// n+16, n+24 -> same XCD under %8 round-robin. XCD k then only touches
// p == k: its w2t slab (512 KB) stays L2-resident and each h-slab is
// L2-served for 3 of its 4 readers.
// ---------------------------------------------------------------------------
__device__ __forceinline__ void decode_tile(int n, int& row_base, int& col_base) {
    const int row_tile = n >> 5;
    const int col_tile = ((n & 7) << 2) | ((n >> 3) & 3);
    row_base = row_tile * 128;
    col_base = col_tile * 128;
}

// ---------------------------------------------------------------------------
// x fp32 -> bf16, 8 elements/thread
// ---------------------------------------------------------------------------
__global__ __launch_bounds__(256) void cvt_x_k(const float* __restrict__ x,
                                               __hip_bfloat16* __restrict__ xb) {
    size_t i = ((size_t)blockIdx.x * 256 + threadIdx.x) * 8;
    float4 v0 = *(const float4*)(x + i);
    float4 v1 = *(const float4*)(x + i + 4);
    union { __hip_bfloat16 h[8]; uint4 u; } r;
    r.h[0] = __float2bfloat16(v0.x); r.h[1] = __float2bfloat16(v0.y);
    r.h[2] = __float2bfloat16(v0.z); r.h[3] = __float2bfloat16(v0.w);
    r.h[4] = __float2bfloat16(v1.x); r.h[5] = __float2bfloat16(v1.y);
    r.h[6] = __float2bfloat16(v1.z); r.h[7] = __float2bfloat16(v1.w);
    *(uint4*)(xb + i) = r.u;
}

// ---------------------------------------------------------------------------
// W[p,d,e] fp32 -> Wt[p,e,d] bf16, optional per-d scale (for W2' = a[d]*W2)
// block (32,8), grid (16,16,8)
// ---------------------------------------------------------------------------
__global__ __launch_bounds__(256) void tr_w_k(const float* __restrict__ W,
                                              const float* __restrict__ scale,
                                              __hip_bfloat16* __restrict__ Wt) {
    __shared__ float t[32][33];
    int p = blockIdx.z;
    int d0 = blockIdx.x * 32, e0 = blockIdx.y * 32;
    const float* Wp = W + (size_t)p * D_BLK * D_BLK;
    for (int j = 0; j < 32; j += 8) {
        int d = d0 + threadIdx.y + j;
        float v = Wp[(size_t)d * D_BLK + e0 + threadIdx.x];
        if (scale) v *= scale[p * D_BLK + d];
        t[threadIdx.y + j][threadIdx.x] = v;
    }
    __syncthreads();
    __hip_bfloat16* Wtp = Wt + (size_t)p * D_BLK * D_BLK;
    for (int j = 0; j < 32; j += 8) {
        int e = e0 + threadIdx.y + j;
        Wtp[(size_t)e * D_BLK + d0 + threadIdx.x] =
            __float2bfloat16(t[threadIdx.x][threadIdx.y + j]);
    }
}

// ---------------------------------------------------------------------------
// finalize BN: a = bn_w * rsqrt(var+eps), c = bn_b - mean*a
// ---------------------------------------------------------------------------
__global__ __launch_bounds__(256) void finalize_k(const float* __restrict__ sum,
                                                  const float* __restrict__ sumsq,
                                                  const float* __restrict__ bnw,
                                                  const float* __restrict__ bnb,
                                                  float* __restrict__ a,
                                                  float* __restrict__ c) {
    int i = blockIdx.x * 256 + threadIdx.x;
    float m = sum[i] * (1.0f / B_ROWS);
    float var = sumsq[i] * (1.0f / B_ROWS) - m * m;
    float ai = bnw[i] * rsqrtf(var + EPSV);
    a[i] = ai;
    c[i] = bnb[i] - m * ai;
}

// ---------------------------------------------------------------------------
// bias2'[col] = bias2[col] + sum_d c[p*D+d] * W2[p,d,e]
// ---------------------------------------------------------------------------
__global__ __launch_bounds__(256) void bias2p_k(const float* __restrict__ W2,
                                                const float* __restrict__ c,
                                                const float* __restrict__ bias2,
                                                float* __restrict__ out) {
    int col = blockIdx.x * 256 + threadIdx.x;
    int p = col >> 9;
    int e = col & (D_BLK - 1);
    const float* Wp = W2 + (size_t)p * D_BLK * D_BLK + e;
    const float* cp = c + p * D_BLK;
    float acc = 0.0f;
    for (int d = 0; d < D_BLK; d++) acc += cp[d] * Wp[(size_t)d * D_BLK];
    out[col] = bias2[col] + acc;
}

// ---------------------------------------------------------------------------
// GEMM core: 128x128 tile, BK=32, single-buffered LDS (R1 structure — dbuf
// was measured neutral-to-negative), 4 waves (2x2), each wave 64x64 via 4x4
// mfma_f32_16x16x32_bf16.
// LDS bank swizzle: chunk position c of row r holds global chunk c^((r>>1)&3)
// (realized by permuting the *source* address; global_load_lds dst is fixed
//  at base+lane*16). Verified: SQ_LDS_BANK_CONFLICT 4.2M -> 0.
// ---------------------------------------------------------------------------
__device__ __forceinline__ void gemm_core(const __hip_bfloat16* __restrict__ A,
                                          const __hip_bfloat16* __restrict__ Bt,
                                          int row_base, int col_base,
                                          f32x4 acc[4][4]) {
    __shared__ __hip_bfloat16 As[128 * 32];
    __shared__ __hip_bfloat16 Bs[128 * 32];

    const int tid = threadIdx.x;
    const int lane = tid & 63;
    const int wave = tid >> 6;
    const int wm = (wave >> 1) * 64;
    const int wn = (wave & 1) * 64;
    const int p = col_base >> 9;
    const int ebase = col_base & (D_BLK - 1);

    // staging: thread tid fills LDS row ar=tid>>2, chunk position c4=tid&3;
    // it must FETCH global chunk q4 = c4 ^ ((ar>>1)&3) = c4 ^ ((tid>>3)&3)
    const int ar = tid >> 2;
    const int c4 = tid & 3;
    const int kq8 = (c4 ^ ((tid >> 3) & 3)) * 8;   // fetched k-offset (elements)
    const int dst_off = ar * 32 + c4 * 8;          // == tid*8 elements = lane*16B

    const __hip_bfloat16* a_src0 = A + (size_t)(row_base + ar) * N_COLS + p * D_BLK + kq8;
    const __hip_bfloat16* a_src1 = a_src0 + (size_t)64 * N_COLS;
    const __hip_bfloat16* b_src0 = Bt + (size_t)(p * D_BLK + ebase + ar) * D_BLK + kq8;
    const __hip_bfloat16* b_src1 = b_src0 + (size_t)64 * D_BLK;
    __hip_bfloat16* a_dst0 = &As[dst_off];
    __hip_bfloat16* a_dst1 = &As[dst_off + 64 * 32];
    __hip_bfloat16* b_dst0 = &Bs[dst_off];
    __hip_bfloat16* b_dst1 = &Bs[dst_off + 64 * 32];

    // fragment read: lane wants row R=...+fm, k-chunk kq=lane>>4; its LDS chunk
    // position is kq ^ ((R>>1)&3) = kq ^ ((fm>>1)&3)  (row bases are mult of 16)
    const int fm = lane & 15;
    const int fkoff = ((lane >> 4) ^ ((fm >> 1) & 3)) * 8;

    for (int i = 0; i < 4; i++)
        for (int j = 0; j < 4; j++)
            acc[i][j] = (f32x4){0.0f, 0.0f, 0.0f, 0.0f};

    for (int k0 = 0; k0 < D_BLK; k0 += 32) {
        async_ld16(a_src0, a_dst0);
        async_ld16(a_src1, a_dst1);
        async_ld16(b_src0, b_dst0);
        async_ld16(b_src1, b_dst1);
        a_src0 += 32; a_src1 += 32; b_src0 += 32; b_src1 += 32;
        __syncthreads();

        bf16x8 af[4], bfr[4];
#pragma unroll
        for (int i = 0; i < 4; i++)
            af[i] = *(const bf16x8*)&As[(wm + i * 16 + fm) * 32 + fkoff];
#pragma unroll
        for (int j = 0; j < 4; j++)
            bfr[j] = *(const bf16x8*)&Bs[(wn + j * 16 + fm) * 32 + fkoff];
#pragma unroll
        for (int i = 0; i < 4; i++)
#pragma unroll
            for (int j = 0; j < 4; j++)
                acc[i][j] = __builtin_amdgcn_mfma_f32_16x16x32_bf16(
                    af[i], bfr[j], acc[i][j], 0, 0, 0);
        __syncthreads();
    }
}

// ---------------------------------------------------------------------------
// GEMM1: h = x @ W1 + bias1 (bf16 out), plus per-column sum / sumsq atomics
// ---------------------------------------------------------------------------
__global__ __launch_bounds__(256) void gemm1_k(const __hip_bfloat16* __restrict__ xb,
                                               const __hip_bfloat16* __restrict__ w1t,
                                               const float* __restrict__ bias1,
                                               __hip_bfloat16* __restrict__ h,
                                               float* __restrict__ sum,
                                               float* __restrict__ sumsq) {
    int row_base, col_base;
    decode_tile(blockIdx.x, row_base, col_base);

    f32x4 acc[4][4];
    gemm_core(xb, w1t, row_base, col_base, acc);

    const int tid = threadIdx.x;
    const int lane = tid & 63;
    const int wave = tid >> 6;
    const int wm = (wave >> 1) * 64;
    const int wn = (wave & 1) * 64;
    const int cr = (lane >> 4) * 4;   // C/D: row = quad*4 + reg
    const int cc = lane & 15;         // C/D: col = lane&15

#pragma unroll
    for (int j = 0; j < 4; j++) {
        const int col = col_base + wn + j * 16 + cc;
        const float b1 = bias1[col];
        float s = 0.0f, sq = 0.0f;
#pragma unroll
        for (int i = 0; i < 4; i++) {
            const int row0 = row_base + wm + i * 16 + cr;
#pragma unroll
            for (int r = 0; r < 4; r++) {
                float v = acc[i][j][r] + b1;
                h[(size_t)(row0 + r) * N_COLS + col] = __float2bfloat16(v);
                s += v;
                sq += v * v;
            }
        }
        s  += __shfl_xor(s, 16);  s  += __shfl_xor(s, 32);
        sq += __shfl_xor(sq, 16); sq += __shfl_xor(sq, 32);
        if (lane < 16) {
            atomicAdd(&sum[col], s);
            atomicAdd(&sumsq[col], sq);
        }
    }
}

// ---------------------------------------------------------------------------
// GEMM2: o3 = h_bf16 @ W2' + bias2' + x ; out = (g + sig(be*o3)*(1-g)) * o3
// residual read from the bf16 copy xb (halves residual fetch traffic)
// ---------------------------------------------------------------------------
__global__ __launch_bounds__(256) void gemm2_k(const __hip_bfloat16* __restrict__ h,
                                               const __hip_bfloat16* __restrict__ w2t,
                                               const float* __restrict__ bias2p,
                                               const __hip_bfloat16* __restrict__ xb,
                                               const float* __restrict__ gamma3,
                                               const float* __restrict__ beta3,
                                               float* __restrict__ out) {
    int row_base, col_base;
    decode_tile(blockIdx.x, row_base, col_base);

    f32x4 acc[4][4];
    gemm_core(h, w2t, row_base, col_base, acc);

    const int tid = threadIdx.x;
    const int lane = tid & 63;
    const int wave = tid >> 6;
    const int wm = (wave >> 1) * 64;
    const int wn = (wave & 1) * 64;
    const int cr = (lane >> 4) * 4;
    const int cc = lane & 15;

#pragma unroll
    for (int j = 0; j < 4; j++) {
        const int col = col_base + wn + j * 16 + cc;
        const float bb = bias2p[col];
        const float g  = gamma3[col];
        const float be = beta3[col];
#pragma unroll
        for (int i = 0; i < 4; i++) {
            const int row0 = row_base + wm + i * 16 + cr;
#pragma unroll
            for (int r = 0; r < 4; r++) {
                const size_t idx = (size_t)(row0 + r) * N_COLS + col;
                float o3 = acc[i][j][r] + bb + __bfloat162float(xb[idx]);
                float sg = 1.0f / (1.0f + expf(-be * o3));
                out[idx] = (g + sg * (1.0f - g)) * o3;
            }
        }
    }
}

// ---------------------------------------------------------------------------
extern "C" void kernel_launch(void* const* d_in, const int* in_sizes, int n_in,
                              void* d_out, int out_size, void* d_ws, size_t ws_size,
                              hipStream_t stream) {
    const float* x     = (const float*)d_in[0];
    const float* W1    = (const float*)d_in[1];
    const float* bias1 = (const float*)d_in[2];
    const float* W2    = (const float*)d_in[3];
    const float* bias2 = (const float*)d_in[4];
    const float* bnw   = (const float*)d_in[5];
    const float* bnb   = (const float*)d_in[6];
    const float* gam3  = (const float*)d_in[7];
    const float* bet3  = (const float*)d_in[8];
    float* out = (float*)d_out;

    // workspace layout
    char* ws = (char*)d_ws;
    const size_t XB_BYTES = (size_t)B_ROWS * N_COLS * 2;   // 64 MiB
    const size_t H_BYTES  = (size_t)B_ROWS * N_COLS * 2;   // 64 MiB
    const size_t WT_BYTES = (size_t)P_BLK * D_BLK * D_BLK * 2;  // 4 MiB
    const size_t V_BYTES  = (size_t)N_COLS * 4;            // 16 KiB

    __hip_bfloat16* xb   = (__hip_bfloat16*)(ws);
    __hip_bfloat16* hbuf = (__hip_bfloat16*)(ws + XB_BYTES);
    __hip_bfloat16* w1t  = (__hip_bfloat16*)(ws + XB_BYTES + H_BYTES);
    __hip_bfloat16* w2t  = (__hip_bfloat16*)(ws + XB_BYTES + H_BYTES + WT_BYTES);
    float* sums  = (float*)(ws + XB_BYTES + H_BYTES + 2 * WT_BYTES);
    float* sumsq = (float*)((char*)sums + V_BYTES);
    float* a_sc  = (float*)((char*)sums + 2 * V_BYTES);
    float* c_sh  = (float*)((char*)sums + 3 * V_BYTES);
    float* b2p   = (float*)((char*)sums + 4 * V_BYTES);

    (void)in_sizes; (void)n_in; (void)out_size; (void)ws_size;

    // zero the stats accumulators (ws is poisoned 0xAA before every call)
    hipMemsetAsync(sums, 0, 2 * V_BYTES, stream);

    // x -> bf16
    cvt_x_k<<<dim3((B_ROWS * N_COLS) / (256 * 8)), dim3(256), 0, stream>>>(x, xb);
    // W1 -> bf16 transposed [p,e,d]
    tr_w_k<<<dim3(16, 16, 8), dim3(32, 8), 0, stream>>>(W1, nullptr, w1t);
    // GEMM1 + bias + stats
    gemm1_k<<<dim3((B_ROWS / 128) * (N_COLS / 128)), dim3(256), 0, stream>>>(
        xb, w1t, bias1, hbuf, sums, sumsq);
    // BN scale/shift
    finalize_k<<<dim3(N_COLS / 256), dim3(256), 0, stream>>>(sums, sumsq, bnw, bnb, a_sc, c_sh);
    // W2' = a * W2, transposed bf16
    tr_w_k<<<dim3(16, 16, 8), dim3(32, 8), 0, stream>>>(W2, a_sc, w2t);
    // bias2' = bias2 + c @ W2
    bias2p_k<<<dim3(N_COLS / 256), dim3(256), 0, stream>>>(W2, c_sh, bias2, b2p);
    // GEMM2 + residual + gate
    gemm2_k<<<dim3((B_ROWS / 128) * (N_COLS / 128)), dim3(256), 0, stream>>>(
        hbuf, w2t, b2p, xb, gam3, bet3, out);
}